// Round 4
// baseline (131.850 us; speedup 1.0000x reference)
//
#include <hip/hip_runtime.h>

// Z: (2049, 8193) fp32, alpha: (1,) fp32.
// out = Z, except last row: out[2048, j] += (alpha/N) * sum_{c<D} v[c]*(Z[c+D,j]-Z[c,j])
// where v[c] = sum_{j<N} Z[2048, j] * Z[c, j]

#define D     1024
#define N     8192
#define DD    2049
#define N1    8193
#define NCOPY 3584
#define NBLK  4608            // 1024 dot blocks interleaved (bid%4==0, bid<4096) + 3584 copy
#define TOTAL4 4196864L       // (2049*8193)/4, remainder 1 element tail

typedef float f32x4  __attribute__((ext_vector_type(4)));              // 16B-aligned
typedef float f32x4u __attribute__((ext_vector_type(4), aligned(4))); // dword-aligned (rows have phase c%4)

// ---------------- Kernel 1: fused copy + dot, interleaved block roles ----------------
__global__ void fused_copy_dot(const float* __restrict__ Z, float* __restrict__ out,
                               float* __restrict__ v) {
    const int bid = blockIdx.x;
    const int t   = threadIdx.x;
    const bool is_dot = (bid < 4096) && ((bid & 3) == 0);
    if (is_dot) {
        const int c = bid >> 2;
        const f32x4u* __restrict__ row = (const f32x4u*)(Z + (long)c * N1);
        const f32x4u* __restrict__ u   = (const f32x4u*)(Z + (long)(DD - 1) * N1);
        float acc = 0.f;
        #pragma unroll
        for (int it = 0; it < 8; ++it) {              // 2048 quads / 256 threads
            const int q = t + it * 256;
            f32x4u a = row[q];
            f32x4u b = u[q];
            acc += a.x * b.x + a.y * b.y + a.z * b.z + a.w * b.w;
        }
        #pragma unroll
        for (int off = 32; off > 0; off >>= 1)
            acc += __shfl_down(acc, off, 64);
        __shared__ float smem[4];
        const int lane = t & 63, wid = t >> 6;
        if (lane == 0) smem[wid] = acc;
        __syncthreads();
        if (t == 0) v[c] = smem[0] + smem[1] + smem[2] + smem[3];
        if (c == 0 && t == 64) {                      // odd tail element of the flat copy
            const long last = (long)DD * N1 - 1;
            out[last] = Z[last];
        }
    } else {
        // copy_id: contiguous 0..3583 over the non-dot blocks
        const int copy_id = (bid < 4096) ? ((bid >> 2) * 3 + (bid & 3) - 1)
                                         : (3072 + (bid - 4096));
        long i = (long)copy_id * 256 + t;
        const long stride = (long)NCOPY * 256;
        const f32x4* __restrict__ src = (const f32x4*)Z;
        f32x4*       __restrict__ dst = (f32x4*)out;
        for (; i < TOTAL4; i += stride) {
            f32x4 val = src[i];
            __builtin_nontemporal_store(val, &dst[i]);
        }
    }
}

// ---------------- Kernel 2: last-row correction, vectorized ----------------
// grid = (8, 64): x covers 2048 float4-quads (j=0..8191), y = 64 splits of 16 c's.
__global__ void corr_kernel(const float* __restrict__ Z, const float* __restrict__ v,
                            const float* __restrict__ alpha, float* __restrict__ out) {
    const int q  = blockIdx.x * 256 + threadIdx.x;    // quad index 0..2047
    const int j0 = q * 4;
    const int c0 = blockIdx.y * 16;
    const float scale = alpha[0] / (float)N;
    float lx = 0.f, ly = 0.f, lz = 0.f, lw = 0.f;
    #pragma unroll
    for (int cc = 0; cc < 16; ++cc) {
        const int c = c0 + cc;
        const float vc = v[c];
        f32x4u zp = *(const f32x4u*)(Z + (long)(c + D) * N1 + j0);
        f32x4u zm = *(const f32x4u*)(Z + (long)c * N1 + j0);
        lx += vc * (zp.x - zm.x);
        ly += vc * (zp.y - zm.y);
        lz += vc * (zp.z - zm.z);
        lw += vc * (zp.w - zm.w);
    }
    float* o = out + (long)(DD - 1) * N1 + j0;
    atomicAdd(o + 0, scale * lx);
    atomicAdd(o + 1, scale * ly);
    atomicAdd(o + 2, scale * lz);
    atomicAdd(o + 3, scale * lw);
    // tail column j = 8192
    if (blockIdx.x == 0 && threadIdx.x == 0) {
        float lt = 0.f;
        for (int cc = 0; cc < 16; ++cc) {
            const int c = c0 + cc;
            lt += v[c] * (Z[(long)(c + D) * N1 + N] - Z[(long)c * N1 + N]);
        }
        atomicAdd(out + (long)(DD - 1) * N1 + N, scale * lt);
    }
}

extern "C" void kernel_launch(void* const* d_in, const int* in_sizes, int n_in,
                              void* d_out, int out_size, void* d_ws, size_t ws_size,
                              hipStream_t stream) {
    const float* Z     = (const float*)d_in[0];
    const float* alpha = (const float*)d_in[1];
    float* out = (float*)d_out;
    float* v   = (float*)d_ws;   // D floats = 4 KB scratch

    fused_copy_dot<<<NBLK, 256, 0, stream>>>(Z, out, v);
    corr_kernel<<<dim3(8, 64), 256, 0, stream>>>(Z, v, alpha, out);
}

// Round 5
// 128.314 us; speedup vs baseline: 1.0276x; 1.0276x over previous
//
#include <hip/hip_runtime.h>

// Z: (2049, 8193) fp32, alpha: (1,) fp32.
// out = Z, except last row: out[2048, j] += (alpha/N) * sum_{c<D} v[c]*(Z[c+D,j]-Z[c,j])
// where v[c] = sum_{j<N} Z[2048, j] * Z[c, j]   (j < N only: M kills column N)

#define D   1024
#define N   8192
#define DD  2049
#define N1  8193

typedef float f32x4u __attribute__((ext_vector_type(4), aligned(4))); // rows start at phase (r*8193)%4 dwords

// ---------------- Kernel 1: row-parallel copy + fused dot ----------------
// grid = 2049 blocks (one per row) x 512 threads. Each thread: 4 quads (16 floats).
// Rows r < 1024 also accumulate v[r] = dot(row, u) over j=0..8191 from the SAME registers.
__global__ void __launch_bounds__(512) copy_dot_rows(const float* __restrict__ Z,
                                                     float* __restrict__ out,
                                                     float* __restrict__ v) {
    const int r = blockIdx.x;
    const int t = threadIdx.x;
    const float* __restrict__ row = Z   + (long)r * N1;
    float*       __restrict__ orow = out + (long)r * N1;
    const float* __restrict__ u   = Z   + (long)(DD - 1) * N1;   // 16B-aligned (2048*8193 % 4 == 0)

    if (r < D) {
        float acc = 0.f;
        #pragma unroll
        for (int it = 0; it < 4; ++it) {
            const int q = t + it * 512;          // quad 0..2047 -> j = 4q..4q+3 (j<8192)
            f32x4u a = *(const f32x4u*)(row + 4 * q);
            f32x4u b = *(const f32x4u*)(u   + 4 * q);
            __builtin_nontemporal_store(a, (f32x4u*)(orow + 4 * q));
            acc += a.x * b.x + a.y * b.y + a.z * b.z + a.w * b.w;
        }
        // reduce 512 threads: wave butterfly then 8-slot LDS
        #pragma unroll
        for (int off = 32; off > 0; off >>= 1)
            acc += __shfl_down(acc, off, 64);
        __shared__ float smem[8];
        if ((t & 63) == 0) smem[t >> 6] = acc;
        __syncthreads();
        if (t == 0) {
            float s = 0.f;
            #pragma unroll
            for (int w = 0; w < 8; ++w) s += smem[w];
            v[r] = s;
        }
    } else {
        #pragma unroll
        for (int it = 0; it < 4; ++it) {
            const int q = t + it * 512;
            f32x4u a = *(const f32x4u*)(row + 4 * q);
            __builtin_nontemporal_store(a, (f32x4u*)(orow + 4 * q));
        }
    }
    if (t == 511) orow[N] = row[N];              // tail element j = 8192 of each row
}

// ---------------- Kernel 2: last-row correction ----------------
// grid = (8, 64): x covers 2048 quads (j=0..8191), y = 64 splits of 16 c's. 4 atomics/thread.
__global__ void corr_kernel(const float* __restrict__ Z, const float* __restrict__ v,
                            const float* __restrict__ alpha, float* __restrict__ out) {
    const int q  = blockIdx.x * 256 + threadIdx.x;   // quad 0..2047
    const int j0 = q * 4;
    const int c0 = blockIdx.y * 16;
    const float scale = alpha[0] / (float)N;
    float lx = 0.f, ly = 0.f, lz = 0.f, lw = 0.f;
    #pragma unroll
    for (int cc = 0; cc < 16; ++cc) {
        const int c = c0 + cc;
        const float vc = v[c];
        f32x4u zp = *(const f32x4u*)(Z + (long)(c + D) * N1 + j0);
        f32x4u zm = *(const f32x4u*)(Z + (long)c * N1 + j0);
        lx += vc * (zp.x - zm.x);
        ly += vc * (zp.y - zm.y);
        lz += vc * (zp.z - zm.z);
        lw += vc * (zp.w - zm.w);
    }
    float* o = out + (long)(DD - 1) * N1 + j0;
    atomicAdd(o + 0, scale * lx);
    atomicAdd(o + 1, scale * ly);
    atomicAdd(o + 2, scale * lz);
    atomicAdd(o + 3, scale * lw);
    // tail column j = 8192 (each y-split adds its 16-c share)
    if (blockIdx.x == 0 && threadIdx.x == 0) {
        float lt = 0.f;
        #pragma unroll
        for (int cc = 0; cc < 16; ++cc) {
            const int c = c0 + cc;
            lt += v[c] * (Z[(long)(c + D) * N1 + N] - Z[(long)c * N1 + N]);
        }
        atomicAdd(out + (long)(DD - 1) * N1 + N, scale * lt);
    }
}

extern "C" void kernel_launch(void* const* d_in, const int* in_sizes, int n_in,
                              void* d_out, int out_size, void* d_ws, size_t ws_size,
                              hipStream_t stream) {
    const float* Z     = (const float*)d_in[0];
    const float* alpha = (const float*)d_in[1];
    float* out = (float*)d_out;
    float* v   = (float*)d_ws;   // D floats = 4 KB scratch

    copy_dot_rows<<<DD, 512, 0, stream>>>(Z, out, v);
    corr_kernel<<<dim3(8, 64), 256, 0, stream>>>(Z, v, alpha, out);
}